// Round 3
// baseline (1250.800 us; speedup 1.0000x reference)
//
#include <hip/hip_runtime.h>

#define N_USERS_P1 50001
#define N_ITEMS_P1 100001
#define N_TOTAL    150002
#define DIM        64
#define N_BEH      2
#define N_EDGES    2000000
#define BATCH      2048
#define ND         ((long)N_TOTAL * DIM)
#define REG_WEIGHT 1e-4f
#define GAMMA_     1e-10f
#define EPS_       1e-9f

// keep the harness-named kernel present (no-op insurance)
__global__ void I_CRGCN_57002805952693_kernel() {}

// zero the 4 scalar accumulators + sentinel into out
__global__ void k_init(float* __restrict__ accums, float* __restrict__ out) {
    if (threadIdx.x < 4) accums[threadIdx.x] = 0.f;
    if (threadIdx.x == 0) out[0] = 0.25f;  // sentinel; overwritten by k_final
}

// zero agg (n4 float4's)
__global__ void k_zero4(float4* __restrict__ p, long n4) {
    long i = (long)blockIdx.x * blockDim.x + threadIdx.x;
    long s = (long)gridDim.x * blockDim.x;
    float4 z = make_float4(0.f, 0.f, 0.f, 0.f);
    for (; i < n4; i += s) p[i] = z;
}

// total = concat(user, item); accumulate sum-of-squares per segment
__global__ void k_build_total(const float* __restrict__ ue,
                              const float* __restrict__ ie,
                              float* __restrict__ total,
                              float* __restrict__ accums) {
    const long NU = (long)N_USERS_P1 * DIM;
    long i = (long)blockIdx.x * blockDim.x + threadIdx.x;
    long s = (long)gridDim.x * blockDim.x;
    float su = 0.f, si = 0.f;
    for (; i < ND; i += s) {
        float v;
        if (i < NU) { v = ue[i];      su += v * v; }
        else        { v = ie[i - NU]; si += v * v; }
        total[i] = v;
    }
    for (int o = 32; o > 0; o >>= 1) {
        su += __shfl_xor(su, o);
        si += __shfl_xor(si, o);
    }
    __shared__ float smu[4], smi[4];
    int w = threadIdx.x >> 6, l = threadIdx.x & 63;
    if (l == 0) { smu[w] = su; smi[w] = si; }
    __syncthreads();
    if (threadIdx.x == 0) {
        float a = 0.f, b = 0.f;
        for (int k = 0; k < 4; k++) { a += smu[k]; b += smi[k]; }
        atomicAdd(&accums[0], a);
        atomicAdd(&accums[1], b);
    }
}

// per-node norm = 1/(den+eps), rscale = sqrt(relu(old*ow))/(den+eps); both behaviors
__global__ void k_norms(const float* __restrict__ now_deg,
                        const float* __restrict__ old_deg,
                        const float* __restrict__ denom_w,
                        const float* __restrict__ oldscale_w,
                        float* __restrict__ norm,
                        float* __restrict__ rscale) {
    int i = blockIdx.x * blockDim.x + threadIdx.x;
    if (i >= N_BEH * N_TOTAL) return;
    float dw = denom_w[0], ow = oldscale_w[0];
    float od = old_deg[i], nd = now_deg[i];
    float den = sqrtf(fmaxf(od * dw, 0.f) + nd);
    float inv = 1.f / (den + EPS_);
    norm[i]   = inv;
    rscale[i] = sqrtf(fmaxf(od * ow, 0.f)) * inv;
}

// edge scatter: agg[dst,:] += norm[src] * total[src,:]   (wave per edge, grid-stride)
__global__ void k_edges(const int* __restrict__ src,
                        const int* __restrict__ dst,
                        const float* __restrict__ norm,
                        const float* __restrict__ total,
                        float* __restrict__ agg) {
    long gid   = (long)blockIdx.x * blockDim.x + threadIdx.x;
    long wave  = gid >> 6;
    int  lane  = (int)(gid & 63);
    long waves = ((long)gridDim.x * blockDim.x) >> 6;
    for (long e = wave; e < N_EDGES; e += waves) {
        int s = src[e], t = dst[e];
        float v = norm[s] * total[(long)s * DIM + lane];
        atomicAdd(&agg[(long)t * DIM + lane], v);
    }
}

// row update (wave per row):
// m = (t + cw00*ls0*rs + cw01*t + cw10*ls1*rs + cw11*norm*agg)/3
// t += m / max(||m||, 1e-12)
__global__ void k_update(float* __restrict__ total,
                         const float* __restrict__ agg,
                         const float* __restrict__ norm,
                         const float* __restrict__ rscale,
                         const float* __restrict__ last_b,   // + b*2*N*D
                         const float* __restrict__ conv_b) { // + b*4
    long gid  = (long)blockIdx.x * blockDim.x + threadIdx.x;
    long row  = gid >> 6;
    int  lane = (int)(gid & 63);
    if (row >= N_TOTAL) return;
    float cw00 = conv_b[0], cw01 = conv_b[1];
    float cw10 = conv_b[2], cw11 = conv_b[3];
    long  off = row * DIM + lane;
    float t   = total[off];
    float e1  = norm[row] * agg[off];
    float ls0 = last_b[off];
    float ls1 = last_b[ND + off];
    float rs  = rscale[row];
    float m = (t + cw00 * ls0 * rs + cw01 * t + cw10 * ls1 * rs + cw11 * e1)
              * (1.f / 3.f);
    float ss = m * m;
    for (int o = 32; o > 0; o >>= 1) ss += __shfl_xor(ss, o);
    float rn = sqrtf(ss);
    total[off] = t + m / fmaxf(rn, 1e-12f);
}

// BPR loss (wave per batch element)
__global__ void k_bpr(const float* __restrict__ total,
                      const int* __restrict__ bdata,  // (BATCH, N_BEH, 3)
                      int b,
                      float* __restrict__ acc) {
    long gid  = (long)blockIdx.x * blockDim.x + threadIdx.x;
    long i    = gid >> 6;
    int  lane = (int)(gid & 63);
    if (i >= BATCH) return;
    const int* row = bdata + (i * N_BEH + b) * 3;
    int iu = row[0];
    int i0 = N_USERS_P1 + row[1];
    int i1 = N_USERS_P1 + row[2];
    float u = total[(long)iu * DIM + lane];
    float a = total[(long)i0 * DIM + lane];
    float c = total[(long)i1 * DIM + lane];
    float s0 = u * a, s1 = u * c;
    for (int o = 32; o > 0; o >>= 1) {
        s0 += __shfl_xor(s0, o);
        s1 += __shfl_xor(s1, o);
    }
    if (lane == 0) {
        float d   = s0 - s1;
        float sig = 1.f / (1.f + expf(-d));
        atomicAdd(acc, -logf(GAMMA_ + sig));
    }
}

__global__ void k_final(const float* __restrict__ accums, float* __restrict__ out) {
    float bpr  = (accums[2] + accums[3]) * (1.f / (float)BATCH);
    float embl = (sqrtf(accums[0]) + sqrtf(accums[1])) / (float)N_ITEMS_P1;
    out[0] = bpr + REG_WEIGHT * embl;
}

extern "C" void kernel_launch(void* const* d_in, const int* in_sizes, int n_in,
                              void* d_out, int out_size, void* d_ws, size_t ws_size,
                              hipStream_t stream) {
    const float* ue      = (const float*)d_in[0];
    const float* ie      = (const float*)d_in[1];
    const float* now_deg = (const float*)d_in[2];
    const float* old_deg = (const float*)d_in[3];
    const float* last    = (const float*)d_in[4];
    const float* denw    = (const float*)d_in[5];
    const float* oldw    = (const float*)d_in[6];
    const float* convw   = (const float*)d_in[7];
    const int*   src     = (const int*)d_in[8];
    const int*   dst     = (const int*)d_in[9];
    const int*   bdata   = (const int*)d_in[10];
    float*       out     = (float*)d_out;

    // ws layout (f32): total[ND] | agg[ND] | norm[2N] | rscale[2N] | accums[4]
    // = 79.3 MB
    float* ws     = (float*)d_ws;
    float* total  = ws;
    float* agg    = total + ND;
    float* norm   = agg + ND;
    float* rscale = norm + 2L * N_TOTAL;
    float* accums = rscale + 2L * N_TOTAL;

    k_init<<<1, 64, 0, stream>>>(accums, out);
    k_build_total<<<2048, 256, 0, stream>>>(ue, ie, total, accums);

    int nb = (N_BEH * N_TOTAL + 255) / 256;
    k_norms<<<nb, 256, 0, stream>>>(now_deg, old_deg, denw, oldw, norm, rscale);

    for (int b = 0; b < N_BEH; b++) {
        k_zero4<<<2048, 256, 0, stream>>>((float4*)agg, ND / 4);
        k_edges<<<16384, 256, 0, stream>>>(
            src + (long)b * N_EDGES, dst + (long)b * N_EDGES,
            norm + (long)b * N_TOTAL, total, agg);
        k_update<<<(N_TOTAL + 3) / 4, 256, 0, stream>>>(
            total, agg, norm + (long)b * N_TOTAL, rscale + (long)b * N_TOTAL,
            last + (long)b * 2 * ND, convw + b * 4);
        k_bpr<<<BATCH / 4, 256, 0, stream>>>(total, bdata, b, &accums[2 + b]);
    }
    k_final<<<1, 1, 0, stream>>>(accums, out);
}

// Round 4
// 1082.594 us; speedup vs baseline: 1.1554x; 1.1554x over previous
//
#include <hip/hip_runtime.h>

#define N_USERS_P1 50001
#define N_ITEMS_P1 100001
#define N_TOTAL    150002
#define DIM        64
#define N_BEH      2
#define N_EDGES    2000000
#define BATCH      2048
#define ND         ((long)N_TOTAL * DIM)
#define REG_WEIGHT 1e-4f
#define GAMMA_     1e-10f
#define EPS_       1e-9f

#define SCAN_CHUNK 1024
#define NB_SCAN    ((N_TOTAL + SCAN_CHUNK - 1) / SCAN_CHUNK)  // 147

// harness-named kernel (unused, kept for safety)
__global__ void I_CRGCN_57002805952693_kernel() {}

__global__ void k_init(float* __restrict__ accums, float* __restrict__ out) {
    if (threadIdx.x < 4) accums[threadIdx.x] = 0.f;
    if (threadIdx.x == 0) out[0] = 0.25f;  // sentinel; overwritten by k_final
}

__global__ void k_zero4(float4* __restrict__ p, long n4) {
    long i = (long)blockIdx.x * blockDim.x + threadIdx.x;
    long s = (long)gridDim.x * blockDim.x;
    float4 z = make_float4(0.f, 0.f, 0.f, 0.f);
    for (; i < n4; i += s) p[i] = z;
}

__global__ void k_zero_int(int* __restrict__ p, int n) {
    int i = blockIdx.x * blockDim.x + threadIdx.x;
    if (i < n) p[i] = 0;
}

// total = concat(user, item); fused Frobenius sum-of-squares (per segment)
__global__ void k_build_total(const float* __restrict__ ue,
                              const float* __restrict__ ie,
                              float* __restrict__ total,
                              float* __restrict__ accums) {
    const long NU = (long)N_USERS_P1 * DIM;
    long i = (long)blockIdx.x * blockDim.x + threadIdx.x;
    long s = (long)gridDim.x * blockDim.x;
    float su = 0.f, si = 0.f;
    for (; i < ND; i += s) {
        float v;
        if (i < NU) { v = ue[i];      su += v * v; }
        else        { v = ie[i - NU]; si += v * v; }
        total[i] = v;
    }
    for (int o = 32; o > 0; o >>= 1) {
        su += __shfl_xor(su, o);
        si += __shfl_xor(si, o);
    }
    __shared__ float smu[4], smi[4];
    int w = threadIdx.x >> 6, l = threadIdx.x & 63;
    if (l == 0) { smu[w] = su; smi[w] = si; }
    __syncthreads();
    if (threadIdx.x == 0) {
        float a = 0.f, b = 0.f;
        for (int k = 0; k < 4; k++) { a += smu[k]; b += smi[k]; }
        atomicAdd(&accums[0], a);
        atomicAdd(&accums[1], b);
    }
}

__global__ void k_norms(const float* __restrict__ now_deg,
                        const float* __restrict__ old_deg,
                        const float* __restrict__ denom_w,
                        const float* __restrict__ oldscale_w,
                        float* __restrict__ norm,
                        float* __restrict__ rscale) {
    int i = blockIdx.x * blockDim.x + threadIdx.x;
    if (i >= N_BEH * N_TOTAL) return;
    float dw = denom_w[0], ow = oldscale_w[0];
    float od = old_deg[i], nd = now_deg[i];
    float den = sqrtf(fmaxf(od * dw, 0.f) + nd);
    float inv = 1.f / (den + EPS_);
    norm[i]   = inv;
    rscale[i] = sqrtf(fmaxf(od * ow, 0.f)) * inv;
}

// ---------- CSR build ----------
__global__ void k_count(const int* __restrict__ dst, int* __restrict__ deg) {
    int i = blockIdx.x * blockDim.x + threadIdx.x;
    if (i < N_EDGES) atomicAdd(&deg[dst[i]], 1);
}

// block-local exclusive scan over 1024-element chunks (256 thr × 4)
__global__ void k_scan1(const int* __restrict__ deg,
                        int* __restrict__ rowptr,
                        int* __restrict__ bsum) {
    __shared__ int sh[256];
    int tid  = threadIdx.x;
    int base = blockIdx.x * SCAN_CHUNK + tid * 4;
    int v0 = 0, v1 = 0, v2 = 0, v3 = 0;
    if (base + 0 < N_TOTAL) v0 = deg[base + 0];
    if (base + 1 < N_TOTAL) v1 = deg[base + 1];
    if (base + 2 < N_TOTAL) v2 = deg[base + 2];
    if (base + 3 < N_TOTAL) v3 = deg[base + 3];
    int s = v0 + v1 + v2 + v3;
    sh[tid] = s;
    __syncthreads();
    for (int off = 1; off < 256; off <<= 1) {
        int t = (tid >= off) ? sh[tid - off] : 0;
        __syncthreads();
        sh[tid] += t;
        __syncthreads();
    }
    int excl = sh[tid] - s;
    if (base + 0 < N_TOTAL) rowptr[base + 0] = excl;
    if (base + 1 < N_TOTAL) rowptr[base + 1] = excl + v0;
    if (base + 2 < N_TOTAL) rowptr[base + 2] = excl + v0 + v1;
    if (base + 3 < N_TOTAL) rowptr[base + 3] = excl + v0 + v1 + v2;
    if (tid == 255) bsum[blockIdx.x] = sh[255];
}

__global__ void k_scan2(int* __restrict__ bsum) {
    if (threadIdx.x == 0 && blockIdx.x == 0) {
        int run = 0;
        for (int i = 0; i < NB_SCAN; i++) { int v = bsum[i]; bsum[i] = run; run += v; }
    }
}

__global__ void k_scan3(int* __restrict__ rowptr, const int* __restrict__ bsum,
                        int* __restrict__ cursor) {
    int i = blockIdx.x * blockDim.x + threadIdx.x;
    if (i >= N_TOTAL) return;
    int v = rowptr[i] + bsum[i / SCAN_CHUNK];
    rowptr[i] = v;
    cursor[i] = v;
}

__global__ void k_fill(const int* __restrict__ src, const int* __restrict__ dst,
                       int* __restrict__ cursor, int* __restrict__ csr_src) {
    int i = blockIdx.x * blockDim.x + threadIdx.x;
    if (i < N_EDGES) {
        int pos = atomicAdd(&cursor[dst[i]], 1);
        csr_src[pos] = src[i];
    }
}

// ---------- fused gather + row update (wave per dst row) ----------
// acc = sum_{s in row} norm[s]*tin[s,:]; e1 = norm[row]*acc
// m = (t + cw00*ls0*rs + cw01*t + cw10*ls1*rs + cw11*e1)/3
// tout = t + m / max(||m||, 1e-12)
__global__ void k_gather_update(const int* __restrict__ rowptr,
                                const int* __restrict__ rowend,
                                const int* __restrict__ csr_src,
                                const float* __restrict__ norm,
                                const float* __restrict__ rscale,
                                const float* __restrict__ tin,
                                float* __restrict__ tout,
                                const float* __restrict__ last_b,   // + b*2*N*D
                                const float* __restrict__ conv_b) { // + b*4
    long gid  = (long)blockIdx.x * blockDim.x + threadIdx.x;
    long row  = gid >> 6;
    int  lane = (int)(gid & 63);
    if (row >= N_TOTAL) return;
    int beg = rowptr[row], end = rowend[row];
    float acc = 0.f;
    int j = beg;
    for (; j + 4 <= end; j += 4) {
        int s0 = csr_src[j], s1 = csr_src[j + 1];
        int s2 = csr_src[j + 2], s3 = csr_src[j + 3];
        float a0 = norm[s0] * tin[(long)s0 * DIM + lane];
        float a1 = norm[s1] * tin[(long)s1 * DIM + lane];
        float a2 = norm[s2] * tin[(long)s2 * DIM + lane];
        float a3 = norm[s3] * tin[(long)s3 * DIM + lane];
        acc += a0 + a1 + a2 + a3;
    }
    for (; j < end; ++j) {
        int s = csr_src[j];
        acc += norm[s] * tin[(long)s * DIM + lane];
    }
    float cw00 = conv_b[0], cw01 = conv_b[1];
    float cw10 = conv_b[2], cw11 = conv_b[3];
    long  off = row * DIM + lane;
    float t   = tin[off];
    float e1  = norm[row] * acc;
    float ls0 = last_b[off];
    float ls1 = last_b[ND + off];
    float rs  = rscale[row];
    float m = (t + cw00 * ls0 * rs + cw01 * t + cw10 * ls1 * rs + cw11 * e1)
              * (1.f / 3.f);
    float ss = m * m;
    for (int o = 32; o > 0; o >>= 1) ss += __shfl_xor(ss, o);
    tout[off] = t + m / fmaxf(sqrtf(ss), 1e-12f);
}

// ---------- fallback (round-3 atomic path) ----------
__global__ void k_edges(const int* __restrict__ src,
                        const int* __restrict__ dst,
                        const float* __restrict__ norm,
                        const float* __restrict__ total,
                        float* __restrict__ agg) {
    long gid   = (long)blockIdx.x * blockDim.x + threadIdx.x;
    long wave  = gid >> 6;
    int  lane  = (int)(gid & 63);
    long waves = ((long)gridDim.x * blockDim.x) >> 6;
    for (long e = wave; e < N_EDGES; e += waves) {
        int s = src[e], t = dst[e];
        float v = norm[s] * total[(long)s * DIM + lane];
        atomicAdd(&agg[(long)t * DIM + lane], v);
    }
}

__global__ void k_update(float* __restrict__ total,
                         const float* __restrict__ agg,
                         const float* __restrict__ norm,
                         const float* __restrict__ rscale,
                         const float* __restrict__ last_b,
                         const float* __restrict__ conv_b) {
    long gid  = (long)blockIdx.x * blockDim.x + threadIdx.x;
    long row  = gid >> 6;
    int  lane = (int)(gid & 63);
    if (row >= N_TOTAL) return;
    float cw00 = conv_b[0], cw01 = conv_b[1];
    float cw10 = conv_b[2], cw11 = conv_b[3];
    long  off = row * DIM + lane;
    float t   = total[off];
    float e1  = norm[row] * agg[off];
    float ls0 = last_b[off];
    float ls1 = last_b[ND + off];
    float rs  = rscale[row];
    float m = (t + cw00 * ls0 * rs + cw01 * t + cw10 * ls1 * rs + cw11 * e1)
              * (1.f / 3.f);
    float ss = m * m;
    for (int o = 32; o > 0; o >>= 1) ss += __shfl_xor(ss, o);
    total[off] = t + m / fmaxf(sqrtf(ss), 1e-12f);
}

__global__ void k_bpr(const float* __restrict__ total,
                      const int* __restrict__ bdata,  // (BATCH, N_BEH, 3)
                      int b,
                      float* __restrict__ acc) {
    long gid  = (long)blockIdx.x * blockDim.x + threadIdx.x;
    long i    = gid >> 6;
    int  lane = (int)(gid & 63);
    if (i >= BATCH) return;
    const int* row = bdata + (i * N_BEH + b) * 3;
    int iu = row[0];
    int i0 = N_USERS_P1 + row[1];
    int i1 = N_USERS_P1 + row[2];
    float u = total[(long)iu * DIM + lane];
    float a = total[(long)i0 * DIM + lane];
    float c = total[(long)i1 * DIM + lane];
    float s0 = u * a, s1 = u * c;
    for (int o = 32; o > 0; o >>= 1) {
        s0 += __shfl_xor(s0, o);
        s1 += __shfl_xor(s1, o);
    }
    if (lane == 0) {
        float d   = s0 - s1;
        float sig = 1.f / (1.f + expf(-d));
        atomicAdd(acc, -logf(GAMMA_ + sig));
    }
}

__global__ void k_final(const float* __restrict__ accums, float* __restrict__ out) {
    float bpr  = (accums[2] + accums[3]) * (1.f / (float)BATCH);
    float embl = (sqrtf(accums[0]) + sqrtf(accums[1])) / (float)N_ITEMS_P1;
    out[0] = bpr + REG_WEIGHT * embl;
}

extern "C" void kernel_launch(void* const* d_in, const int* in_sizes, int n_in,
                              void* d_out, int out_size, void* d_ws, size_t ws_size,
                              hipStream_t stream) {
    const float* ue      = (const float*)d_in[0];
    const float* ie      = (const float*)d_in[1];
    const float* now_deg = (const float*)d_in[2];
    const float* old_deg = (const float*)d_in[3];
    const float* last    = (const float*)d_in[4];
    const float* denw    = (const float*)d_in[5];
    const float* oldw    = (const float*)d_in[6];
    const float* convw   = (const float*)d_in[7];
    const int*   src     = (const int*)d_in[8];
    const int*   dst     = (const int*)d_in[9];
    const int*   bdata   = (const int*)d_in[10];
    float*       out     = (float*)d_out;

    // ws layout: total_a[ND] | total_b[ND] | norm[2N] | rscale[2N] | accums[8]
    //            | rowptr[N] | cursor[N] | bsum[256] | csr[N_EDGES]  ≈ 88.4 MB
    float* ws      = (float*)d_ws;
    float* total_a = ws;
    float* total_b = total_a + ND;
    float* norm    = total_b + ND;
    float* rscale  = norm + 2L * N_TOTAL;
    float* accums  = rscale + 2L * N_TOTAL;
    int*   rowptr  = (int*)(accums + 8);
    int*   cursor  = rowptr + N_TOTAL;
    int*   bsum    = cursor + N_TOTAL;
    int*   csr     = bsum + 256;
    size_t required = (size_t)((char*)(csr + N_EDGES) - (char*)d_ws);

    k_init<<<1, 64, 0, stream>>>(accums, out);
    k_build_total<<<2048, 256, 0, stream>>>(ue, ie, total_a, accums);
    k_norms<<<(N_BEH * N_TOTAL + 255) / 256, 256, 0, stream>>>(
        now_deg, old_deg, denw, oldw, norm, rscale);

    const int nbE = (N_EDGES + 255) / 256;
    const int nbN = (N_TOTAL + 255) / 256;
    const int nbR = (N_TOTAL + 3) / 4;  // wave per row, 4 rows/block

    if (ws_size >= required) {
        // CSR + gather path (ping-pong total buffers)
        const float* tin = total_a;
        float*       tout = total_b;
        for (int b = 0; b < N_BEH; b++) {
            const int* srcb = src + (long)b * N_EDGES;
            const int* dstb = dst + (long)b * N_EDGES;
            k_zero_int<<<nbN, 256, 0, stream>>>(cursor, N_TOTAL);  // cursor = deg
            k_count<<<nbE, 256, 0, stream>>>(dstb, cursor);
            k_scan1<<<NB_SCAN, 256, 0, stream>>>(cursor, rowptr, bsum);
            k_scan2<<<1, 64, 0, stream>>>(bsum);
            k_scan3<<<nbN, 256, 0, stream>>>(rowptr, bsum, cursor);
            k_fill<<<nbE, 256, 0, stream>>>(srcb, dstb, cursor, csr);
            k_gather_update<<<nbR, 256, 0, stream>>>(
                rowptr, cursor, csr,
                norm + (long)b * N_TOTAL, rscale + (long)b * N_TOTAL,
                tin, tout, last + (long)b * 2 * ND, convw + b * 4);
            k_bpr<<<BATCH / 4, 256, 0, stream>>>(tout, bdata, b, &accums[2 + b]);
            float* t = (float*)tin; tin = tout; tout = t;
        }
    } else {
        // fallback: round-3 atomic scatter (total=total_a, agg=total_b)
        for (int b = 0; b < N_BEH; b++) {
            k_zero4<<<2048, 256, 0, stream>>>((float4*)total_b, ND / 4);
            k_edges<<<16384, 256, 0, stream>>>(
                src + (long)b * N_EDGES, dst + (long)b * N_EDGES,
                norm + (long)b * N_TOTAL, total_a, total_b);
            k_update<<<nbR, 256, 0, stream>>>(
                total_a, total_b, norm + (long)b * N_TOTAL,
                rscale + (long)b * N_TOTAL, last + (long)b * 2 * ND, convw + b * 4);
            k_bpr<<<BATCH / 4, 256, 0, stream>>>(total_a, bdata, b, &accums[2 + b]);
        }
    }
    k_final<<<1, 1, 0, stream>>>(accums, out);
}